// Round 1
// baseline (417.340 us; speedup 1.0000x reference)
//
#include <hip/hip_runtime.h>
#include <hip/hip_bf16.h>

#define N_NODES 100000
#define N_EDGES 1250000
#define DIM 64

// Kernel 1: y1 = x @ W1 -> out (pre-relu accumulator), y2 = x @ W2 -> ws.
// One thread per row. W rows are wave-uniform loads -> scalar loads + SGPR-operand FMAs.
__global__ __launch_bounds__(256) void gemm_dual(
    const float* __restrict__ x,
    const float* __restrict__ W1,
    const float* __restrict__ W2,
    float* __restrict__ y1,
    float* __restrict__ y2,
    int n) {
  int row = blockIdx.x * blockDim.x + threadIdx.x;
  if (row >= n) return;

  float xv[DIM];
  const float4* xr = (const float4*)(x + (size_t)row * DIM);
#pragma unroll
  for (int i = 0; i < DIM / 4; ++i) {
    float4 t = xr[i];
    xv[4 * i + 0] = t.x;
    xv[4 * i + 1] = t.y;
    xv[4 * i + 2] = t.z;
    xv[4 * i + 3] = t.w;
  }

  float acc[DIM];

  // --- W1 ---
#pragma unroll
  for (int c = 0; c < DIM; ++c) acc[c] = 0.0f;
  for (int k = 0; k < DIM; ++k) {
    float xk = xv[k];
    const float* wrow = W1 + k * DIM;
#pragma unroll
    for (int c = 0; c < DIM; ++c) acc[c] = fmaf(xk, wrow[c], acc[c]);
  }
  {
    float4* o = (float4*)(y1 + (size_t)row * DIM);
#pragma unroll
    for (int i = 0; i < DIM / 4; ++i)
      o[i] = make_float4(acc[4 * i], acc[4 * i + 1], acc[4 * i + 2], acc[4 * i + 3]);
  }

  // --- W2 ---
#pragma unroll
  for (int c = 0; c < DIM; ++c) acc[c] = 0.0f;
  for (int k = 0; k < DIM; ++k) {
    float xk = xv[k];
    const float* wrow = W2 + k * DIM;
#pragma unroll
    for (int c = 0; c < DIM; ++c) acc[c] = fmaf(xk, wrow[c], acc[c]);
  }
  {
    float4* o = (float4*)(y2 + (size_t)row * DIM);
#pragma unroll
    for (int i = 0; i < DIM / 4; ++i)
      o[i] = make_float4(acc[4 * i], acc[4 * i + 1], acc[4 * i + 2], acc[4 * i + 3]);
  }
}

// Kernel 2: one wave per edge. lane j: atomicAdd(out[dst*64+j], y2[src*64+j]).
__global__ __launch_bounds__(256) void scatter_add(
    const int* __restrict__ ei,      // [2, E] flat: src at [e], dst at [E + e]
    const float* __restrict__ y2,
    float* __restrict__ out,
    int nE) {
  int gid = blockIdx.x * blockDim.x + threadIdx.x;
  int edge = gid >> 6;
  int lane = threadIdx.x & 63;
  if (edge >= nE) return;

  // Force wave-uniform (scalar) index loads.
  int src = __builtin_amdgcn_readfirstlane(ei[edge]);
  int dst = __builtin_amdgcn_readfirstlane(ei[nE + edge]);

  float v = y2[(size_t)src * DIM + lane];
  atomicAdd(&out[(size_t)dst * DIM + lane], v);
}

// Kernel 3: in-place relu, float4 vectorized.
__global__ __launch_bounds__(256) void relu_inplace(float* __restrict__ out, int n4) {
  int i = blockIdx.x * blockDim.x + threadIdx.x;
  if (i >= n4) return;
  float4* p = (float4*)out;
  float4 v = p[i];
  v.x = fmaxf(v.x, 0.0f);
  v.y = fmaxf(v.y, 0.0f);
  v.z = fmaxf(v.z, 0.0f);
  v.w = fmaxf(v.w, 0.0f);
  p[i] = v;
}

extern "C" void kernel_launch(void* const* d_in, const int* in_sizes, int n_in,
                              void* d_out, int out_size, void* d_ws, size_t ws_size,
                              hipStream_t stream) {
  const float* x  = (const float*)d_in[0];
  const int*   ei = (const int*)d_in[1];
  const float* W1 = (const float*)d_in[2];
  const float* W2 = (const float*)d_in[3];
  float* out = (float*)d_out;
  float* y2  = (float*)d_ws;   // N_NODES * DIM floats = 25.6 MB

  // 1) y1 -> out, y2 -> ws
  {
    int blocks = (N_NODES + 255) / 256;
    gemm_dual<<<blocks, 256, 0, stream>>>(x, W1, W2, out, y2, N_NODES);
  }
  // 2) scatter-add edges into out
  {
    long long threads = (long long)N_EDGES * 64;
    int blocks = (int)((threads + 255) / 256);
    scatter_add<<<blocks, 256, 0, stream>>>(ei, y2, out, N_EDGES);
  }
  // 3) relu
  {
    int n4 = N_NODES * DIM / 4;
    int blocks = (n4 + 255) / 256;
    relu_inplace<<<blocks, 256, 0, stream>>>(out, n4);
  }
}

// Round 2
// 346.483 us; speedup vs baseline: 1.2045x; 1.2045x over previous
//
#include <hip/hip_runtime.h>
#include <hip/hip_bf16.h>

#define N_NODES 100000
#define N_EDGES 1250000
#define DIM 64
#define NB_SCAN ((N_NODES + 255) / 256)   // 391 blocks of 256 for the scan

static __host__ __device__ inline size_t align256(size_t x) { return (x + 255) & ~(size_t)255; }

// ---------------- GEMM: y1 = x@W1 -> out, y2 = x@W2 -> ws ----------------
// One thread per row; acc chunked to 16 to keep VGPRs ~95 (≈5 waves/SIMD).
// W accesses are block-uniform -> compiler emits s_loads (1 SGPR operand/FMA).
__global__ __launch_bounds__(256) void gemm_dual(
    const float* __restrict__ x,
    const float* __restrict__ W1,
    const float* __restrict__ W2,
    float* __restrict__ y1,
    float* __restrict__ y2,
    int n) {
  int row = blockIdx.x * blockDim.x + threadIdx.x;
  if (row >= n) return;

  float xv[DIM];
  const float4* xr = (const float4*)(x + (size_t)row * DIM);
#pragma unroll
  for (int i = 0; i < DIM / 4; ++i) {
    float4 t = xr[i];
    xv[4 * i + 0] = t.x;
    xv[4 * i + 1] = t.y;
    xv[4 * i + 2] = t.z;
    xv[4 * i + 3] = t.w;
  }

#pragma unroll
  for (int m = 0; m < 2; ++m) {
    const float* W = (m == 0) ? W1 : W2;
    float* Y = ((m == 0) ? y1 : y2) + (size_t)row * DIM;
#pragma unroll
    for (int cc = 0; cc < DIM; cc += 16) {
      float acc[16];
#pragma unroll
      for (int c = 0; c < 16; ++c) acc[c] = 0.0f;
      for (int k = 0; k < DIM; ++k) {
        float xk = xv[k];
        const float* wr = W + k * DIM + cc;
#pragma unroll
        for (int c = 0; c < 16; ++c) acc[c] = fmaf(xk, wr[c], acc[c]);
      }
      float4* o = (float4*)(Y + cc);
#pragma unroll
      for (int i = 0; i < 4; ++i)
        o[i] = make_float4(acc[4 * i], acc[4 * i + 1], acc[4 * i + 2], acc[4 * i + 3]);
    }
  }
}

// ---------------- CSR build ----------------
__global__ __launch_bounds__(256) void hist_kernel(const int* __restrict__ ei,
                                                   int* __restrict__ counts, int nE) {
  int e = blockIdx.x * blockDim.x + threadIdx.x;
  if (e >= nE) return;
  atomicAdd(&counts[ei[nE + e]], 1);
}

// Block-level exclusive scan; emits per-block totals.
__global__ __launch_bounds__(256) void scan1_kernel(const int* __restrict__ counts,
                                                    int* __restrict__ offs,
                                                    int* __restrict__ blockSums, int n) {
  __shared__ int tmp[256];
  int gid = blockIdx.x * 256 + threadIdx.x;
  int v = (gid < n) ? counts[gid] : 0;
  tmp[threadIdx.x] = v;
  __syncthreads();
#pragma unroll
  for (int off = 1; off < 256; off <<= 1) {
    int t = (threadIdx.x >= off) ? tmp[threadIdx.x - off] : 0;
    __syncthreads();
    tmp[threadIdx.x] += t;
    __syncthreads();
  }
  int incl = tmp[threadIdx.x];
  if (gid < n) offs[gid] = incl - v;
  if (threadIdx.x == 255) blockSums[blockIdx.x] = incl;
}

// Single-block exclusive scan of the 391 block sums.
__global__ __launch_bounds__(512) void scan2_kernel(int* __restrict__ blockSums, int nb) {
  __shared__ int tmp[512];
  int i = threadIdx.x;
  int v = (i < nb) ? blockSums[i] : 0;
  tmp[i] = v;
  __syncthreads();
#pragma unroll
  for (int off = 1; off < 512; off <<= 1) {
    int t = (i >= off) ? tmp[i - off] : 0;
    __syncthreads();
    tmp[i] += t;
    __syncthreads();
  }
  if (i < nb) blockSums[i] = tmp[i] - v;
}

// Add block offsets, copy to cursor, write sentinel.
__global__ __launch_bounds__(256) void scan3_kernel(int* __restrict__ offs,
                                                    const int* __restrict__ blockSums,
                                                    int* __restrict__ cursor, int n, int nE) {
  int gid = blockIdx.x * 256 + threadIdx.x;
  if (gid < n) {
    int v = offs[gid] + blockSums[blockIdx.x];
    offs[gid] = v;
    cursor[gid] = v;
  }
  if (gid == 0) offs[n] = nE;
}

__global__ __launch_bounds__(256) void fill_kernel(const int* __restrict__ ei,
                                                   int* __restrict__ cursor,
                                                   int* __restrict__ srcs, int nE) {
  int e = blockIdx.x * blockDim.x + threadIdx.x;
  if (e >= nE) return;
  int dst = ei[nE + e];
  int pos = atomicAdd(&cursor[dst], 1);
  srcs[pos] = ei[e];
}

// ---------------- Gather + self + relu ----------------
// One wave per dst node; lane j owns feature j. Per edge: one coalesced 256B
// read of y2[src]. Edge list / offsets are wave-uniform -> scalar loads.
__global__ __launch_bounds__(256) void gather_finalize(
    const int* __restrict__ offs,
    const int* __restrict__ srcs,
    const float* __restrict__ y2,
    float* __restrict__ out,   // holds y1 on input
    int n) {
  int gid = blockIdx.x * blockDim.x + threadIdx.x;
  int node = __builtin_amdgcn_readfirstlane(gid >> 6);
  int lane = threadIdx.x & 63;
  if (node >= n) return;

  int begin = offs[node];
  int end = offs[node + 1];

  float a0 = 0.f, a1 = 0.f, a2 = 0.f, a3 = 0.f;
  int e = begin;
  for (; e + 3 < end; e += 4) {
    int s0 = srcs[e + 0];
    int s1 = srcs[e + 1];
    int s2 = srcs[e + 2];
    int s3 = srcs[e + 3];
    a0 += y2[(size_t)s0 * DIM + lane];
    a1 += y2[(size_t)s1 * DIM + lane];
    a2 += y2[(size_t)s2 * DIM + lane];
    a3 += y2[(size_t)s3 * DIM + lane];
  }
  for (; e < end; ++e) a0 += y2[(size_t)srcs[e] * DIM + lane];

  float acc = (a0 + a1) + (a2 + a3);
  size_t idx = (size_t)node * DIM + lane;
  out[idx] = fmaxf(out[idx] + acc, 0.0f);
}

// ---------------- Fallback path (round-1 atomics) ----------------
__global__ __launch_bounds__(256) void scatter_add(const int* __restrict__ ei,
                                                   const float* __restrict__ y2,
                                                   float* __restrict__ out, int nE) {
  int gid = blockIdx.x * blockDim.x + threadIdx.x;
  int edge = gid >> 6;
  int lane = threadIdx.x & 63;
  if (edge >= nE) return;
  int src = __builtin_amdgcn_readfirstlane(ei[edge]);
  int dst = __builtin_amdgcn_readfirstlane(ei[nE + edge]);
  atomicAdd(&out[(size_t)dst * DIM + lane], y2[(size_t)src * DIM + lane]);
}

__global__ __launch_bounds__(256) void relu_inplace(float* __restrict__ out, int n4) {
  int i = blockIdx.x * blockDim.x + threadIdx.x;
  if (i >= n4) return;
  float4* p = (float4*)out;
  float4 v = p[i];
  v.x = fmaxf(v.x, 0.0f);
  v.y = fmaxf(v.y, 0.0f);
  v.z = fmaxf(v.z, 0.0f);
  v.w = fmaxf(v.w, 0.0f);
  p[i] = v;
}

extern "C" void kernel_launch(void* const* d_in, const int* in_sizes, int n_in,
                              void* d_out, int out_size, void* d_ws, size_t ws_size,
                              hipStream_t stream) {
  const float* x  = (const float*)d_in[0];
  const int*   ei = (const int*)d_in[1];
  const float* W1 = (const float*)d_in[2];
  const float* W2 = (const float*)d_in[3];
  float* out = (float*)d_out;

  // Workspace layout (256B-aligned regions)
  char* ws = (char*)d_ws;
  size_t off = 0;
  float* y2 = (float*)(ws + off);          off += align256((size_t)N_NODES * DIM * sizeof(float));
  int* counts = (int*)(ws + off);          off += align256((size_t)N_NODES * sizeof(int));
  int* offs = (int*)(ws + off);            off += align256((size_t)(N_NODES + 1) * sizeof(int));
  int* cursor = (int*)(ws + off);          off += align256((size_t)N_NODES * sizeof(int));
  int* blockSums = (int*)(ws + off);       off += align256((size_t)512 * sizeof(int));
  int* srcs = (int*)(ws + off);            off += align256((size_t)N_EDGES * sizeof(int));
  size_t required = off;

  // 1) GEMMs: y1 -> out, y2 -> ws
  {
    int blocks = (N_NODES + 255) / 256;
    gemm_dual<<<blocks, 256, 0, stream>>>(x, W1, W2, out, y2, N_NODES);
  }

  if (ws_size >= required) {
    // 2) CSR build
    hipMemsetAsync(counts, 0, (size_t)N_NODES * sizeof(int), stream);
    {
      int blocks = (N_EDGES + 255) / 256;
      hist_kernel<<<blocks, 256, 0, stream>>>(ei, counts, N_EDGES);
    }
    scan1_kernel<<<NB_SCAN, 256, 0, stream>>>(counts, offs, blockSums, N_NODES);
    scan2_kernel<<<1, 512, 0, stream>>>(blockSums, NB_SCAN);
    scan3_kernel<<<NB_SCAN, 256, 0, stream>>>(offs, blockSums, cursor, N_NODES, N_EDGES);
    {
      int blocks = (N_EDGES + 255) / 256;
      fill_kernel<<<blocks, 256, 0, stream>>>(ei, cursor, srcs, N_EDGES);
    }
    // 3) Gather + self + relu (one wave per node)
    {
      long long threads = (long long)N_NODES * 64;
      int blocks = (int)((threads + 255) / 256);
      gather_finalize<<<blocks, 256, 0, stream>>>(offs, srcs, y2, out, N_NODES);
    }
  } else {
    // Fallback: atomic scatter (round-1 path)
    {
      long long threads = (long long)N_EDGES * 64;
      int blocks = (int)((threads + 255) / 256);
      scatter_add<<<blocks, 256, 0, stream>>>(ei, y2, out, N_EDGES);
    }
    {
      int n4 = N_NODES * DIM / 4;
      int blocks = (n4 + 255) / 256;
      relu_inplace<<<blocks, 256, 0, stream>>>(out, n4);
    }
  }
}